// Round 6
// baseline (680.839 us; speedup 1.0000x reference)
//
#include <hip/hip_runtime.h>
#include <cmath>

#define NEG -1e9f
#define LOG2E 1.44269504088896340736f
constexpr int B = 8, N = 512, M = 512, D = 512;
constexpr size_t NM = (size_t)N * M;   // 262144

// CH = 16: chunk = barrier interval = wave skew (16 diagonals per chunk).
// Forward: wave w active chunks [5w, 5w+35]; backward: [35-5w, 70-5w], K0=1134.
constexpr int NCHUNK = 72;      // even; compute chunks end at 70

// Native-hardware transcendentals (v_exp_f32 = 2^x, v_log_f32 = log2 x).
#define EXP2F(x) __builtin_amdgcn_exp2f(x)
#define LOG2F(x) __builtin_amdgcn_logf(x)

typedef float f32x2 __attribute__((ext_vector_type(2)));

// Prefetch load as inline asm: the def is an asm output -> cannot be
// rematerialized at use or sunk; the value MUST stay in VGPRs.
#define GLOAD(dst, ptr) \
    asm volatile("global_load_dwordx2 %0, %1, off" : "=v"(dst) : "v"(ptr))

// DPP full-wave shifts (register-file; replaces ds_bpermute).
__device__ __forceinline__ float dpp_shr1(float v) {
    return __int_as_float(__builtin_amdgcn_update_dpp(
        __float_as_int(v), __float_as_int(v), 0x138, 0xf, 0xf, false));
}
__device__ __forceinline__ float dpp_shl1(float v) {
    return __int_as_float(__builtin_amdgcn_update_dpp(
        __float_as_int(v), __float_as_int(v), 0x130, 0xf, 0xf, false));
}

// Compact diagonal layout: cell (r,c) 0-based -> diag_off(kd) + r - max(0,kd-511)
__device__ __forceinline__ int diag_off(int kd) {
    return (kd <= 511) ? ((kd * (kd + 1)) >> 1)
                       : ((int)NM - (((1023 - kd) * (1024 - kd)) >> 1));
}
__device__ __forceinline__ int diag_flat_clamped(int kd, int r) {
    const int k = min(max(kd, 0), 1022);
    const int f = diag_off(k) + r - max(0, k - 511);
    return min(max(f, 0), (int)NM - 1);
}

// ---------------------------------------------------------------------------
// GEMM + activation: which=0 -> theta = softplus(zx . zy^T)
//                    which=1 -> A     = log_sigmoid(gx . gy^T)
// ---------------------------------------------------------------------------
__global__ __launch_bounds__(256)
void gemm_act_kernel(const float* __restrict__ zx, const float* __restrict__ zy,
                     const float* __restrict__ gx, const float* __restrict__ gy,
                     float* __restrict__ out_theta, float* __restrict__ out_A)
{
    const int bz = blockIdx.z;
    const int b = bz >> 1, which = bz & 1;
    const float* X = (which ? gx : zx) + (size_t)b * N * D;
    const float* Y = (which ? gy : zy) + (size_t)b * M * D;
    float* C = (which ? out_A : out_theta) + (size_t)b * NM;

    __shared__ float Xs[16][68];
    __shared__ float Ys[16][68];

    const int tx = threadIdx.x, ty = threadIdx.y;
    const int t = ty * 16 + tx;
    const int lrow = t >> 2;
    const int lk4 = (t & 3) * 4;
    const int row0 = blockIdx.y * 64, col0 = blockIdx.x * 64;

    float acc[4][4] = {};

    for (int k0 = 0; k0 < D; k0 += 16) {
        const float4 xv = *(const float4*)&X[(row0 + lrow) * D + k0 + lk4];
        const float4 yv = *(const float4*)&Y[(col0 + lrow) * D + k0 + lk4];
        Xs[lk4 + 0][lrow] = xv.x; Xs[lk4 + 1][lrow] = xv.y;
        Xs[lk4 + 2][lrow] = xv.z; Xs[lk4 + 3][lrow] = xv.w;
        Ys[lk4 + 0][lrow] = yv.x; Ys[lk4 + 1][lrow] = yv.y;
        Ys[lk4 + 2][lrow] = yv.z; Ys[lk4 + 3][lrow] = yv.w;
        __syncthreads();
#pragma unroll
        for (int kk = 0; kk < 16; kk++) {
            const float4 a = *(const float4*)&Xs[kk][ty * 4];
            const float4 bb = *(const float4*)&Ys[kk][tx * 4];
            acc[0][0] += a.x * bb.x; acc[0][1] += a.x * bb.y; acc[0][2] += a.x * bb.z; acc[0][3] += a.x * bb.w;
            acc[1][0] += a.y * bb.x; acc[1][1] += a.y * bb.y; acc[1][2] += a.y * bb.z; acc[1][3] += a.y * bb.w;
            acc[2][0] += a.z * bb.x; acc[2][1] += a.z * bb.y; acc[2][2] += a.z * bb.z; acc[2][3] += a.z * bb.w;
            acc[3][0] += a.w * bb.x; acc[3][1] += a.w * bb.y; acc[3][2] += a.w * bb.z; acc[3][3] += a.w * bb.w;
        }
        __syncthreads();
    }

#pragma unroll
    for (int r = 0; r < 4; r++) {
        float4 o;
        float* op = &o.x;
#pragma unroll
        for (int c = 0; c < 4; c++) {
            const float x = acc[r][c];
            const float l = log1pf(expf(-fabsf(x)));
            op[c] = which ? (fminf(x, 0.0f) - l)     // log_sigmoid
                          : (fmaxf(x, 0.0f) + l);   // softplus
        }
        *(float4*)&C[(size_t)(row0 + ty * 4 + r) * M + col0 + tx * 4] = o;
    }
}

// ---------------------------------------------------------------------------
// Row-major theta,A -> compact-diag interleaved float2 {theta, A}, scaled by
// log2(e) so the DP kernel can use native exp2/log2 (p-ratios are invariant).
// ---------------------------------------------------------------------------
__global__ __launch_bounds__(256)
void reorder_in_kernel(const float* __restrict__ theta, const float* __restrict__ A,
                       float2* __restrict__ TAD)
{
    __shared__ float T[64][67];
    __shared__ float Ag[64][67];
    const int b = blockIdx.z;
    const float* ts = theta + (size_t)b * NM;
    const float* as = A + (size_t)b * NM;
    float2* dst = TAD + (size_t)b * NM;
    const int r0 = blockIdx.y * 64, c0 = blockIdx.x * 64;
    const int t = threadIdx.x, lane = t & 63, wv = t >> 6;

#pragma unroll
    for (int e = 0; e < 16; e++) {
        const int r = wv * 16 + e;
        T[r][lane]  = ts[(size_t)(r0 + r) * M + c0 + lane];
        Ag[r][lane] = as[(size_t)(r0 + r) * M + c0 + lane];
    }
    __syncthreads();
    for (int dd = wv; dd < 127; dd += 4) {
        const int kd = r0 + c0 + dd;
        const int rlo = max(0, dd - 63);
        const int L = min(63, dd) - rlo + 1;
        if (lane < L) {
            const int rloc = rlo + lane;
            const int gr = r0 + rloc;
            dst[diag_off(kd) + gr - max(0, kd - 511)] =
                make_float2(T[rloc][dd - rloc] * LOG2E, Ag[rloc][dd - rloc] * LOG2E);
        }
    }
}

// ---------------------------------------------------------------------------
// Compact-diag E -> row-major aln.
// ---------------------------------------------------------------------------
__global__ __launch_bounds__(256)
void reorder_out_kernel(const float* __restrict__ ED, float* __restrict__ aln)
{
    __shared__ float T[64][67];
    const int b = blockIdx.z;
    const float* src = ED + (size_t)b * NM;
    float* dst = aln + (size_t)b * NM;
    const int r0 = blockIdx.y * 64, c0 = blockIdx.x * 64;
    const int t = threadIdx.x, lane = t & 63, wv = t >> 6;

    for (int dd = wv; dd < 127; dd += 4) {
        const int kd = r0 + c0 + dd;
        const int rlo = max(0, dd - 63);
        const int L = min(63, dd) - rlo + 1;
        if (lane < L) {
            const int rloc = rlo + lane;
            const int gr = r0 + rloc;
            T[rloc][dd - rloc] = src[diag_off(kd) + gr - max(0, kd - 511)];
        }
    }
    __syncthreads();
#pragma unroll
    for (int e = 0; e < 16; e++) {
        const int r = wv * 16 + e;
        dst[(size_t)(r0 + r) * M + c0 + lane] = T[r][lane];
    }
}

// ---------------------------------------------------------------------------
// Chunk-top fence: drain in-flight loads for CUR (issued one chunk ago ->
// steady-state ~0 wait) and old stores; sched_barrier stops compute hoisting
// above the wait (rule #18).
// ---------------------------------------------------------------------------
#define VMCNT_TOP                              \
    asm volatile("s_waitcnt vmcnt(0)");        \
    __builtin_amdgcn_sched_barrier(0);

// Chunk barrier: LDS drain + raw s_barrier (next-chunk loads stay in flight).
#define CHUNK_BARRIER                          \
    __builtin_amdgcn_sched_barrier(0);         \
    asm volatile("s_waitcnt lgkmcnt(0)");      \
    __builtin_amdgcn_s_barrier();              \
    __builtin_amdgcn_sched_barrier(0);

#define DECL16(P) f32x2 P##0, P##1, P##2, P##3, P##4, P##5, P##6, P##7, \
                        P##8, P##9, P##10, P##11, P##12, P##13, P##14, P##15;

// ---------------------------------------------------------------------------
// Forward soft-NW. CH=16 wave pipeline; asm-issued register prefetch
// (immune to sink/remat); base-2 math; interior chunks drop per-lane guards.
// ---------------------------------------------------------------------------
#define F_ISSUE(P, c1) {                                       \
    const int kb1 = 16 * (c1) - w16;                           \
    GLOAD(P##0,  &tabv[diag_flat_clamped(kb1 + 0,  tid)]);     \
    GLOAD(P##1,  &tabv[diag_flat_clamped(kb1 + 1,  tid)]);     \
    GLOAD(P##2,  &tabv[diag_flat_clamped(kb1 + 2,  tid)]);     \
    GLOAD(P##3,  &tabv[diag_flat_clamped(kb1 + 3,  tid)]);     \
    GLOAD(P##4,  &tabv[diag_flat_clamped(kb1 + 4,  tid)]);     \
    GLOAD(P##5,  &tabv[diag_flat_clamped(kb1 + 5,  tid)]);     \
    GLOAD(P##6,  &tabv[diag_flat_clamped(kb1 + 6,  tid)]);     \
    GLOAD(P##7,  &tabv[diag_flat_clamped(kb1 + 7,  tid)]);     \
    GLOAD(P##8,  &tabv[diag_flat_clamped(kb1 + 8,  tid)]);     \
    GLOAD(P##9,  &tabv[diag_flat_clamped(kb1 + 9,  tid)]);     \
    GLOAD(P##10, &tabv[diag_flat_clamped(kb1 + 10, tid)]);     \
    GLOAD(P##11, &tabv[diag_flat_clamped(kb1 + 11, tid)]);     \
    GLOAD(P##12, &tabv[diag_flat_clamped(kb1 + 12, tid)]);     \
    GLOAD(P##13, &tabv[diag_flat_clamped(kb1 + 13, tid)]);     \
    GLOAD(P##14, &tabv[diag_flat_clamped(kb1 + 14, tid)]);     \
    GLOAD(P##15, &tabv[diag_flat_clamped(kb1 + 15, tid)]);     \
}

#define F_CORE(kd_, TA, sh1v, dgv) {                           \
    const float th = (TA).x, a = (TA).y;                       \
    const float x0 = a + sh1v;                                 \
    const float x2 = a + vprev;                                \
    const float mx = fmaxf(fmaxf(x0, dgv), x2);                \
    const float e0 = EXP2F(x0 - mx);                           \
    const float e1 = EXP2F(dgv - mx);                          \
    const float e2 = EXP2F(x2 - mx);                           \
    const float sum = e0 + e1 + e2;                            \
    const float inv = __builtin_amdgcn_rcpf(sum);              \
    const int fi = diag_off(kd_) + tid - max(0, (kd_) - 511);  \
    pb[fi] = make_float2(e0 * inv, e2 * inv);                  \
    vprev = th + mx + LOG2F(sum);                              \
    if (lane == 63) ring[w][(kd_) & 63] = vprev;               \
}

// interior: every lane valid, jj>=1 guaranteed -> no selects, no exec juggling
#define F_STEP_I(s, TA, RG) {                                  \
    const int kd = kb + (s);                                   \
    float sh1 = dpp_shr1(vprev);                               \
    if (lane == 0) sh1 = RG;                                   \
    const float dgv = sh1_d;                                   \
    sh1_d = sh1;                                               \
    F_CORE(kd, TA, sh1, dgv)                                   \
}

#define F_STEP_G(s, TA, RG) {                                  \
    const int kd = kb + (s);                                   \
    const int jj = kd - tid;                                   \
    float sh1 = dpp_shr1(vprev);                               \
    if (lane == 0) sh1 = RG;                                   \
    const float dgv = (jj == 0) ? ((tid == 0) ? 0.0f : NEG) : sh1_d; \
    sh1_d = sh1;                                               \
    if (jj >= 0 && jj < M) { F_CORE(kd, TA, sh1, dgv) }        \
}

#define F_STEPS(SFX, CUR)                                              \
    F_STEP_##SFX(0,  CUR##0,  r0)  F_STEP_##SFX(1,  CUR##1,  r1)       \
    F_STEP_##SFX(2,  CUR##2,  r2)  F_STEP_##SFX(3,  CUR##3,  r3)       \
    F_STEP_##SFX(4,  CUR##4,  r4)  F_STEP_##SFX(5,  CUR##5,  r5)       \
    F_STEP_##SFX(6,  CUR##6,  r6)  F_STEP_##SFX(7,  CUR##7,  r7)       \
    F_STEP_##SFX(8,  CUR##8,  r8)  F_STEP_##SFX(9,  CUR##9,  r9)       \
    F_STEP_##SFX(10, CUR##10, r10) F_STEP_##SFX(11, CUR##11, r11)      \
    F_STEP_##SFX(12, CUR##12, r12) F_STEP_##SFX(13, CUR##13, r13)      \
    F_STEP_##SFX(14, CUR##14, r14) F_STEP_##SFX(15, CUR##15, r15)

#define F_CHUNK(c_, CUR, NXT) {                                \
    const int c = (c_);                                        \
    VMCNT_TOP                /* CUR loads now valid */         \
    F_ISSUE(NXT, c + 1)      /* overlap with compute below */  \
    if (c >= ca && c <= cb) {                                  \
        const int kb = 16 * c - w16;                           \
        float r0 = NEG, r1 = NEG, r2 = NEG, r3 = NEG,          \
              r4 = NEG, r5 = NEG, r6 = NEG, r7 = NEG,          \
              r8 = NEG, r9 = NEG, r10 = NEG, r11 = NEG,        \
              r12 = NEG, r13 = NEG, r14 = NEG, r15 = NEG;      \
        if (w > 0) {                                           \
            r0  = ring[w - 1][(kb - 1) & 63];                  \
            r1  = ring[w - 1][(kb + 0) & 63];                  \
            r2  = ring[w - 1][(kb + 1) & 63];                  \
            r3  = ring[w - 1][(kb + 2) & 63];                  \
            r4  = ring[w - 1][(kb + 3) & 63];                  \
            r5  = ring[w - 1][(kb + 4) & 63];                  \
            r6  = ring[w - 1][(kb + 5) & 63];                  \
            r7  = ring[w - 1][(kb + 6) & 63];                  \
            r8  = ring[w - 1][(kb + 7) & 63];                  \
            r9  = ring[w - 1][(kb + 8) & 63];                  \
            r10 = ring[w - 1][(kb + 9) & 63];                  \
            r11 = ring[w - 1][(kb + 10) & 63];                 \
            r12 = ring[w - 1][(kb + 11) & 63];                 \
            r13 = ring[w - 1][(kb + 12) & 63];                 \
            r14 = ring[w - 1][(kb + 13) & 63];                 \
            r15 = ring[w - 1][(kb + 14) & 63];                 \
        }                                                      \
        const int kr = kb - 64 * w;                            \
        if (kr >= 64 && kr <= 496) {                           \
            F_STEPS(I, CUR)                                    \
        } else {                                               \
            F_STEPS(G, CUR)                                    \
        }                                                      \
    }                                                          \
    CHUNK_BARRIER                                              \
}

__global__ __launch_bounds__(512, 1)
void nw_forward_kernel(const float2* __restrict__ TAD, float2* __restrict__ pD)
{
    __shared__ float ring[8][64];
    const int b = blockIdx.x;
    const int tid = threadIdx.x;
    const int w = __builtin_amdgcn_readfirstlane(tid >> 6);
    const int lane = tid & 63;
    const int w16 = 16 * w;
    const float2* tab = TAD + (size_t)b * NM;
    const f32x2* __restrict__ tabv = (const f32x2*)tab;
    float2* pb = pD + (size_t)b * NM;

    for (int x = tid; x < 8 * 64; x += 512) ((float*)ring)[x] = NEG;
    __syncthreads();

    const int ca = 5 * w, cb = 5 * w + 35;

    DECL16(fa) DECL16(fb)
    F_ISSUE(fa, 0)

    float vprev = NEG, sh1_d = NEG;

    for (int c2 = 0; c2 < NCHUNK; c2 += 2) {
        F_CHUNK(c2 + 0, fa, fb)
        F_CHUNK(c2 + 1, fb, fa)
    }
}

// ---------------------------------------------------------------------------
// Backward adjoint, q-product form, mirrored skew (wave 7 leads), K0 = 1134.
// Same asm-prefetch + raw-barrier + interior-specialization, CH=16.
// ---------------------------------------------------------------------------
#define B_ISSUE(P, c1) {                                       \
    const int kb1 = 1134 - 16 * (c1) - w16;                    \
    GLOAD(P##0,  &pbv[diag_flat_clamped(kb1 - 0,  tid)]);      \
    GLOAD(P##1,  &pbv[diag_flat_clamped(kb1 - 1,  tid)]);      \
    GLOAD(P##2,  &pbv[diag_flat_clamped(kb1 - 2,  tid)]);      \
    GLOAD(P##3,  &pbv[diag_flat_clamped(kb1 - 3,  tid)]);      \
    GLOAD(P##4,  &pbv[diag_flat_clamped(kb1 - 4,  tid)]);      \
    GLOAD(P##5,  &pbv[diag_flat_clamped(kb1 - 5,  tid)]);      \
    GLOAD(P##6,  &pbv[diag_flat_clamped(kb1 - 6,  tid)]);      \
    GLOAD(P##7,  &pbv[diag_flat_clamped(kb1 - 7,  tid)]);      \
    GLOAD(P##8,  &pbv[diag_flat_clamped(kb1 - 8,  tid)]);      \
    GLOAD(P##9,  &pbv[diag_flat_clamped(kb1 - 9,  tid)]);      \
    GLOAD(P##10, &pbv[diag_flat_clamped(kb1 - 10, tid)]);      \
    GLOAD(P##11, &pbv[diag_flat_clamped(kb1 - 11, tid)]);      \
    GLOAD(P##12, &pbv[diag_flat_clamped(kb1 - 12, tid)]);      \
    GLOAD(P##13, &pbv[diag_flat_clamped(kb1 - 13, tid)]);      \
    GLOAD(P##14, &pbv[diag_flat_clamped(kb1 - 14, tid)]);      \
    GLOAD(P##15, &pbv[diag_flat_clamped(kb1 - 15, tid)]);      \
}

#define B_CORE(kd_, PP, suv, sdv, TERMFIX) {                   \
    float e = suv + sdv + ql1;                                 \
    TERMFIX                                                    \
    const float pu = (PP).x, pl = (PP).y;                      \
    const float pd = 1.0f - pu - pl;                           \
    const float qu = pu * e, qd = pd * e, ql = pl * e;         \
    const int fi = diag_off(kd_) + tid - max(0, (kd_) - 511);  \
    eb[fi] = e;                                                \
    qd2 = qd1; qd1 = qd; qu1 = qu; ql1 = ql;                   \
    if (lane == 0) {                                           \
        ring_u[w][(kd_) & 63] = qu;                            \
        ring_d[w][(kd_) & 63] = qd;                            \
    }                                                          \
}

#define B_STEP_I(s, PP, RU, RD) {                              \
    const int kd = kb - (s);                                   \
    float su = dpp_shl1(qu1);                                  \
    float sd = dpp_shl1(qd2);                                  \
    if (lane == 63) { su = RU; sd = RD; }                      \
    B_CORE(kd, PP, su, sd, )                                   \
}

#define B_STEP_G(s, PP, RU, RD) {                              \
    const int kd = kb - (s);                                   \
    const int jj = kd - tid;                                   \
    float su = dpp_shl1(qu1);                                  \
    float sd = dpp_shl1(qd2);                                  \
    if (lane == 63) { su = RU; sd = RD; }                      \
    if (jj >= 0 && jj < M) {                                   \
        B_CORE(kd, PP, su, sd,                                 \
               if (tid == N - 1 && jj == M - 1) e = 1.0f;)     \
    }                                                          \
}

#define B_STEPS(SFX, CUR)                                                \
    B_STEP_##SFX(0,  CUR##0,  ru0,  rd0)  B_STEP_##SFX(1,  CUR##1,  ru1,  rd1)  \
    B_STEP_##SFX(2,  CUR##2,  ru2,  rd2)  B_STEP_##SFX(3,  CUR##3,  ru3,  rd3)  \
    B_STEP_##SFX(4,  CUR##4,  ru4,  rd4)  B_STEP_##SFX(5,  CUR##5,  ru5,  rd5)  \
    B_STEP_##SFX(6,  CUR##6,  ru6,  rd6)  B_STEP_##SFX(7,  CUR##7,  ru7,  rd7)  \
    B_STEP_##SFX(8,  CUR##8,  ru8,  rd8)  B_STEP_##SFX(9,  CUR##9,  ru9,  rd9)  \
    B_STEP_##SFX(10, CUR##10, ru10, rd10) B_STEP_##SFX(11, CUR##11, ru11, rd11) \
    B_STEP_##SFX(12, CUR##12, ru12, rd12) B_STEP_##SFX(13, CUR##13, ru13, rd13) \
    B_STEP_##SFX(14, CUR##14, ru14, rd14) B_STEP_##SFX(15, CUR##15, ru15, rd15)

#define B_CHUNK(c_, CUR, NXT) {                                \
    const int c = (c_);                                        \
    VMCNT_TOP                                                  \
    B_ISSUE(NXT, c + 1)                                        \
    if (c >= ca && c <= cb) {                                  \
        const int kb = 1134 - 16 * c - w16;                    \
        float ru0 = 0.f, ru1 = 0.f, ru2 = 0.f, ru3 = 0.f,      \
              ru4 = 0.f, ru5 = 0.f, ru6 = 0.f, ru7 = 0.f,      \
              ru8 = 0.f, ru9 = 0.f, ru10 = 0.f, ru11 = 0.f,    \
              ru12 = 0.f, ru13 = 0.f, ru14 = 0.f, ru15 = 0.f;  \
        float rd0 = 0.f, rd1 = 0.f, rd2 = 0.f, rd3 = 0.f,      \
              rd4 = 0.f, rd5 = 0.f, rd6 = 0.f, rd7 = 0.f,      \
              rd8 = 0.f, rd9 = 0.f, rd10 = 0.f, rd11 = 0.f,    \
              rd12 = 0.f, rd13 = 0.f, rd14 = 0.f, rd15 = 0.f;  \
        if (w < 7) {                                           \
            ru0  = ring_u[w + 1][(kb + 1)  & 63]; rd0  = ring_d[w + 1][(kb + 2)  & 63]; \
            ru1  = ring_u[w + 1][(kb + 0)  & 63]; rd1  = ring_d[w + 1][(kb + 1)  & 63]; \
            ru2  = ring_u[w + 1][(kb - 1)  & 63]; rd2  = ring_d[w + 1][(kb + 0)  & 63]; \
            ru3  = ring_u[w + 1][(kb - 2)  & 63]; rd3  = ring_d[w + 1][(kb - 1)  & 63]; \
            ru4  = ring_u[w + 1][(kb - 3)  & 63]; rd4  = ring_d[w + 1][(kb - 2)  & 63]; \
            ru5  = ring_u[w + 1][(kb - 4)  & 63]; rd5  = ring_d[w + 1][(kb - 3)  & 63]; \
            ru6  = ring_u[w + 1][(kb - 5)  & 63]; rd6  = ring_d[w + 1][(kb - 4)  & 63]; \
            ru7  = ring_u[w + 1][(kb - 6)  & 63]; rd7  = ring_d[w + 1][(kb - 5)  & 63]; \
            ru8  = ring_u[w + 1][(kb - 7)  & 63]; rd8  = ring_d[w + 1][(kb - 6)  & 63]; \
            ru9  = ring_u[w + 1][(kb - 8)  & 63]; rd9  = ring_d[w + 1][(kb - 7)  & 63]; \
            ru10 = ring_u[w + 1][(kb - 9)  & 63]; rd10 = ring_d[w + 1][(kb - 8)  & 63]; \
            ru11 = ring_u[w + 1][(kb - 10) & 63]; rd11 = ring_d[w + 1][(kb - 9)  & 63]; \
            ru12 = ring_u[w + 1][(kb - 11) & 63]; rd12 = ring_d[w + 1][(kb - 10) & 63]; \
            ru13 = ring_u[w + 1][(kb - 12) & 63]; rd13 = ring_d[w + 1][(kb - 11) & 63]; \
            ru14 = ring_u[w + 1][(kb - 13) & 63]; rd14 = ring_d[w + 1][(kb - 12) & 63]; \
            ru15 = ring_u[w + 1][(kb - 14) & 63]; rd15 = ring_d[w + 1][(kb - 13) & 63]; \
        }                                                      \
        const int krb = kb - 64 * w;                           \
        if (krb >= 78 && krb <= 511) {                         \
            B_STEPS(I, CUR)                                    \
        } else {                                               \
            B_STEPS(G, CUR)                                    \
        }                                                      \
    }                                                          \
    CHUNK_BARRIER                                              \
}

__global__ __launch_bounds__(512, 1)
void nw_backward_kernel(const float2* __restrict__ pD, float* __restrict__ ED)
{
    __shared__ float ring_u[8][64];
    __shared__ float ring_d[8][64];
    const int b = blockIdx.x;
    const int tid = threadIdx.x;
    const int w = __builtin_amdgcn_readfirstlane(tid >> 6);
    const int lane = tid & 63;
    const int w16 = 16 * w;
    const float2* pb = pD + (size_t)b * NM;
    const f32x2* __restrict__ pbv = (const f32x2*)pb;
    float* eb = ED + (size_t)b * NM;

    for (int x = tid; x < 8 * 64; x += 512) {
        ((float*)ring_u)[x] = 0.0f;
        ((float*)ring_d)[x] = 0.0f;
    }
    __syncthreads();

    const int ca = 35 - 5 * w, cb = 70 - 5 * w;

    DECL16(ba) DECL16(bb)
    B_ISSUE(ba, 0)

    float qu1 = 0.0f, qd1 = 0.0f, qd2 = 0.0f, ql1 = 0.0f;

    for (int c2 = 0; c2 < NCHUNK; c2 += 2) {
        B_CHUNK(c2 + 0, ba, bb)
        B_CHUNK(c2 + 1, bb, ba)
    }
}

// ---------------------------------------------------------------------------
extern "C" void kernel_launch(void* const* d_in, const int* in_sizes, int n_in,
                              void* d_out, int out_size, void* d_ws, size_t ws_size,
                              hipStream_t stream) {
    const float* zx = (const float*)d_in[0];
    const float* zy = (const float*)d_in[1];
    const float* gx = (const float*)d_in[2];
    const float* gy = (const float*)d_in[3];

    float* aln   = (float*)d_out;               // output 0: [B,N,M]
    float* theta = aln + B * NM;                // output 1
    float* Amat  = theta + B * NM;              // output 2

    float2* TAD = (float2*)d_ws;                // {theta,A}*log2e diag-interleaved
    float2* pD  = TAD + B * NM;                 // {p_up,p_lf} diag-interleaved
    float*  ED  = (float*)d_ws;                 // overlays TAD (dead after forward)

    gemm_act_kernel<<<dim3(8, 8, B * 2), dim3(16, 16), 0, stream>>>(zx, zy, gx, gy, theta, Amat);
    reorder_in_kernel<<<dim3(8, 8, B), 256, 0, stream>>>(theta, Amat, TAD);
    nw_forward_kernel<<<B, 512, 0, stream>>>(TAD, pD);
    nw_backward_kernel<<<B, 512, 0, stream>>>(pD, ED);
    reorder_out_kernel<<<dim3(8, 8, B), 256, 0, stream>>>(ED, aln);
}

// Round 7
// 558.029 us; speedup vs baseline: 1.2201x; 1.2201x over previous
//
#include <hip/hip_runtime.h>
#include <cmath>

#define NEG -1e9f
#define LOG2E 1.44269504088896340736f
constexpr int B = 8, N = 512, M = 512, D = 512;
constexpr size_t NM = (size_t)N * M;   // 262144

// CH = 16: chunk = barrier interval = wave skew (16 diagonals per chunk).
// Forward: wave w active chunks [5w, 5w+35]; backward: [35-5w, 70-5w], K0=1134.
constexpr int NCHUNK = 72;      // even; compute chunks end at 70

// Native-hardware transcendentals (v_exp_f32 = 2^x, v_log_f32 = log2 x).
#define EXP2F(x) __builtin_amdgcn_exp2f(x)
#define LOG2F(x) __builtin_amdgcn_logf(x)

typedef float f32x2 __attribute__((ext_vector_type(2)));

// DPP full-wave shifts (register-file; replaces ds_bpermute).
__device__ __forceinline__ float dpp_shr1(float v) {
    return __int_as_float(__builtin_amdgcn_update_dpp(
        __float_as_int(v), __float_as_int(v), 0x138, 0xf, 0xf, false));
}
__device__ __forceinline__ float dpp_shl1(float v) {
    return __int_as_float(__builtin_amdgcn_update_dpp(
        __float_as_int(v), __float_as_int(v), 0x130, 0xf, 0xf, false));
}

// Compact diagonal layout: cell (r,c) 0-based -> diag_off(kd) + r - max(0,kd-511)
__device__ __forceinline__ int diag_off(int kd) {
    return (kd <= 511) ? ((kd * (kd + 1)) >> 1)
                       : ((int)NM - (((1023 - kd) * (1024 - kd)) >> 1));
}

// ---------------------------------------------------------------------------
// GEMM + activation: which=0 -> theta = softplus(zx . zy^T)
//                    which=1 -> A     = log_sigmoid(gx . gy^T)
// ---------------------------------------------------------------------------
__global__ __launch_bounds__(256)
void gemm_act_kernel(const float* __restrict__ zx, const float* __restrict__ zy,
                     const float* __restrict__ gx, const float* __restrict__ gy,
                     float* __restrict__ out_theta, float* __restrict__ out_A)
{
    const int bz = blockIdx.z;
    const int b = bz >> 1, which = bz & 1;
    const float* X = (which ? gx : zx) + (size_t)b * N * D;
    const float* Y = (which ? gy : zy) + (size_t)b * M * D;
    float* C = (which ? out_A : out_theta) + (size_t)b * NM;

    __shared__ float Xs[16][68];
    __shared__ float Ys[16][68];

    const int tx = threadIdx.x, ty = threadIdx.y;
    const int t = ty * 16 + tx;
    const int lrow = t >> 2;
    const int lk4 = (t & 3) * 4;
    const int row0 = blockIdx.y * 64, col0 = blockIdx.x * 64;

    float acc[4][4] = {};

    for (int k0 = 0; k0 < D; k0 += 16) {
        const float4 xv = *(const float4*)&X[(row0 + lrow) * D + k0 + lk4];
        const float4 yv = *(const float4*)&Y[(col0 + lrow) * D + k0 + lk4];
        Xs[lk4 + 0][lrow] = xv.x; Xs[lk4 + 1][lrow] = xv.y;
        Xs[lk4 + 2][lrow] = xv.z; Xs[lk4 + 3][lrow] = xv.w;
        Ys[lk4 + 0][lrow] = yv.x; Ys[lk4 + 1][lrow] = yv.y;
        Ys[lk4 + 2][lrow] = yv.z; Ys[lk4 + 3][lrow] = yv.w;
        __syncthreads();
#pragma unroll
        for (int kk = 0; kk < 16; kk++) {
            const float4 a = *(const float4*)&Xs[kk][ty * 4];
            const float4 bb = *(const float4*)&Ys[kk][tx * 4];
            acc[0][0] += a.x * bb.x; acc[0][1] += a.x * bb.y; acc[0][2] += a.x * bb.z; acc[0][3] += a.x * bb.w;
            acc[1][0] += a.y * bb.x; acc[1][1] += a.y * bb.y; acc[1][2] += a.y * bb.z; acc[1][3] += a.y * bb.w;
            acc[2][0] += a.z * bb.x; acc[2][1] += a.z * bb.y; acc[2][2] += a.z * bb.z; acc[2][3] += a.z * bb.w;
            acc[3][0] += a.w * bb.x; acc[3][1] += a.w * bb.y; acc[3][2] += a.w * bb.z; acc[3][3] += a.w * bb.w;
        }
        __syncthreads();
    }

#pragma unroll
    for (int r = 0; r < 4; r++) {
        float4 o;
        float* op = &o.x;
#pragma unroll
        for (int c = 0; c < 4; c++) {
            const float x = acc[r][c];
            const float l = log1pf(expf(-fabsf(x)));
            op[c] = which ? (fminf(x, 0.0f) - l)     // log_sigmoid
                          : (fmaxf(x, 0.0f) + l);   // softplus
        }
        *(float4*)&C[(size_t)(row0 + ty * 4 + r) * M + col0 + tx * 4] = o;
    }
}

// ---------------------------------------------------------------------------
// Row-major theta,A -> compact-diag interleaved float2 {theta, A}, scaled by
// log2(e) so the DP kernel can use native exp2/log2 (p-ratios are invariant).
// ---------------------------------------------------------------------------
__global__ __launch_bounds__(256)
void reorder_in_kernel(const float* __restrict__ theta, const float* __restrict__ A,
                       float2* __restrict__ TAD)
{
    __shared__ float T[64][67];
    __shared__ float Ag[64][67];
    const int b = blockIdx.z;
    const float* ts = theta + (size_t)b * NM;
    const float* as = A + (size_t)b * NM;
    float2* dst = TAD + (size_t)b * NM;
    const int r0 = blockIdx.y * 64, c0 = blockIdx.x * 64;
    const int t = threadIdx.x, lane = t & 63, wv = t >> 6;

#pragma unroll
    for (int e = 0; e < 16; e++) {
        const int r = wv * 16 + e;
        T[r][lane]  = ts[(size_t)(r0 + r) * M + c0 + lane];
        Ag[r][lane] = as[(size_t)(r0 + r) * M + c0 + lane];
    }
    __syncthreads();
    for (int dd = wv; dd < 127; dd += 4) {
        const int kd = r0 + c0 + dd;
        const int rlo = max(0, dd - 63);
        const int L = min(63, dd) - rlo + 1;
        if (lane < L) {
            const int rloc = rlo + lane;
            const int gr = r0 + rloc;
            dst[diag_off(kd) + gr - max(0, kd - 511)] =
                make_float2(T[rloc][dd - rloc] * LOG2E, Ag[rloc][dd - rloc] * LOG2E);
        }
    }
}

// ---------------------------------------------------------------------------
// Compact-diag E -> row-major aln.
// ---------------------------------------------------------------------------
__global__ __launch_bounds__(256)
void reorder_out_kernel(const float* __restrict__ ED, float* __restrict__ aln)
{
    __shared__ float T[64][67];
    const int b = blockIdx.z;
    const float* src = ED + (size_t)b * NM;
    float* dst = aln + (size_t)b * NM;
    const int r0 = blockIdx.y * 64, c0 = blockIdx.x * 64;
    const int t = threadIdx.x, lane = t & 63, wv = t >> 6;

    for (int dd = wv; dd < 127; dd += 4) {
        const int kd = r0 + c0 + dd;
        const int rlo = max(0, dd - 63);
        const int L = min(63, dd) - rlo + 1;
        if (lane < L) {
            const int rloc = rlo + lane;
            const int gr = r0 + rloc;
            T[rloc][dd - rloc] = src[diag_off(kd) + gr - max(0, kd - 511)];
        }
    }
    __syncthreads();
#pragma unroll
    for (int e = 0; e < 16; e++) {
        const int r = wv * 16 + e;
        dst[(size_t)(r0 + r) * M + c0 + lane] = T[r][lane];
    }
}

// ---------------------------------------------------------------------------
// Fences. VMCNT_TOP: CUR loads (issued one chunk ago) are complete after this.
// CHUNK_BARRIER: LDS drain + raw s_barrier; next-chunk loads stay in flight.
// ---------------------------------------------------------------------------
#define VMCNT_TOP                              \
    asm volatile("s_waitcnt vmcnt(0)");        \
    __builtin_amdgcn_sched_barrier(0);

#define CHUNK_BARRIER                          \
    __builtin_amdgcn_sched_barrier(0);         \
    asm volatile("s_waitcnt lgkmcnt(0)");      \
    __builtin_amdgcn_s_barrier();              \
    __builtin_amdgcn_sched_barrier(0);

#define DECL16(P)  f32x2 P##0, P##1, P##2, P##3, P##4, P##5, P##6, P##7, \
                         P##8, P##9, P##10, P##11, P##12, P##13, P##14, P##15;
#define DECL16F(P) float P##0, P##1, P##2, P##3, P##4, P##5, P##6, P##7, \
                         P##8, P##9, P##10, P##11, P##12, P##13, P##14, P##15;

// ---------------------------------------------------------------------------
// Forward soft-NW. Rolled chunk loop (I$-resident body), streaming incremental
// diag addressing (running byte offset, SGPR-base loads/stores), asm-issued
// register prefetch, batched stores, base-2 math.
// Load stream: kdl ascending, delta = (kd<=510 ? max(kd+1,0) : max(1022-kd,0)).
// Store stream: kds ascending from 64w (first active diagonal of wave w).
// ---------------------------------------------------------------------------
#define FLOAD1(dst) {                                          \
    asm volatile("global_load_dwordx2 %0, %1, %2"              \
                 : "=v"(dst) : "v"(off8l), "s"(tab));          \
    const int d_ = (kdl <= 510) ? max(kdl + 1, 0)              \
                                : max(1022 - kdl, 0);          \
    off8l += d_ * 8; kdl++;                                    \
}
#define F_ISSUE(P) {                                           \
    FLOAD1(P##0)  FLOAD1(P##1)  FLOAD1(P##2)  FLOAD1(P##3)     \
    FLOAD1(P##4)  FLOAD1(P##5)  FLOAD1(P##6)  FLOAD1(P##7)     \
    FLOAD1(P##8)  FLOAD1(P##9)  FLOAD1(P##10) FLOAD1(P##11)    \
    FLOAD1(P##12) FLOAD1(P##13) FLOAD1(P##14) FLOAD1(P##15)    \
}

#define F_CORE(kd_, TA, sh1v, dgv, O) {                        \
    const float th = (TA).x, a = (TA).y;                       \
    const float x0 = a + sh1v;                                 \
    const float x2 = a + vprev;                                \
    const float mx = fmaxf(fmaxf(x0, dgv), x2);                \
    const float e0 = EXP2F(x0 - mx);                           \
    const float e1 = EXP2F(dgv - mx);                          \
    const float e2 = EXP2F(x2 - mx);                           \
    const float sum = e0 + e1 + e2;                            \
    const float inv = __builtin_amdgcn_rcpf(sum);              \
    (O).x = e0 * inv; (O).y = e2 * inv;                        \
    vprev = th + mx + LOG2F(sum);                              \
    if (lane == 63) ring[w][(kd_) & 63] = vprev;               \
}

// interior: every lane valid, jj>=1 guaranteed -> no selects, no exec juggling
#define F_STEP_I(s, TA, O, RG) {                               \
    const int kd = kb + (s);                                   \
    float sh1 = dpp_shr1(vprev);                               \
    if (lane == 0) sh1 = RG;                                   \
    const float dgv = sh1_d;                                   \
    sh1_d = sh1;                                               \
    F_CORE(kd, TA, sh1, dgv, O)                                \
}

#define F_STEP_G(s, TA, O, RG) {                               \
    const int kd = kb + (s);                                   \
    const int jj = kd - tid;                                   \
    float sh1 = dpp_shr1(vprev);                               \
    if (lane == 0) sh1 = RG;                                   \
    const float dgv = (jj == 0) ? ((tid == 0) ? 0.0f : NEG) : sh1_d; \
    sh1_d = sh1;                                               \
    if (jj >= 0 && jj < M) { F_CORE(kd, TA, sh1, dgv, O) }     \
}

#define F_STEPS(SFX, CUR)                                                    \
    F_STEP_##SFX(0,  CUR##0,  o0,  r0)  F_STEP_##SFX(1,  CUR##1,  o1,  r1)   \
    F_STEP_##SFX(2,  CUR##2,  o2,  r2)  F_STEP_##SFX(3,  CUR##3,  o3,  r3)   \
    F_STEP_##SFX(4,  CUR##4,  o4,  r4)  F_STEP_##SFX(5,  CUR##5,  o5,  r5)   \
    F_STEP_##SFX(6,  CUR##6,  o6,  r6)  F_STEP_##SFX(7,  CUR##7,  o7,  r7)   \
    F_STEP_##SFX(8,  CUR##8,  o8,  r8)  F_STEP_##SFX(9,  CUR##9,  o9,  r9)   \
    F_STEP_##SFX(10, CUR##10, o10, r10) F_STEP_##SFX(11, CUR##11, o11, r11)  \
    F_STEP_##SFX(12, CUR##12, o12, r12) F_STEP_##SFX(13, CUR##13, o13, r13)  \
    F_STEP_##SFX(14, CUR##14, o14, r14) F_STEP_##SFX(15, CUR##15, o15, r15)

#define F_ADV_S { const int d_ = (kds <= 510) ? (kds + 1) : (1022 - kds);    \
                  off8s += d_ * 8; kds++; }
#define FST_I(O) {                                                           \
    asm volatile("global_store_dwordx2 %0, %1, %2"                           \
                 :: "v"(off8s), "v"(O), "s"(pb) : "memory");                 \
    F_ADV_S }
#define FST_G(s, O) {                                                        \
    const int jj = kb + (s) - tid;                                           \
    if (jj >= 0 && jj < M) {                                                 \
        asm volatile("global_store_dwordx2 %0, %1, %2"                       \
                     :: "v"(off8s), "v"(O), "s"(pb) : "memory"); }           \
    F_ADV_S }
#define F_STORES_I {                                                         \
    FST_I(o0)  FST_I(o1)  FST_I(o2)  FST_I(o3)                               \
    FST_I(o4)  FST_I(o5)  FST_I(o6)  FST_I(o7)                               \
    FST_I(o8)  FST_I(o9)  FST_I(o10) FST_I(o11)                              \
    FST_I(o12) FST_I(o13) FST_I(o14) FST_I(o15) }
#define F_STORES_G {                                                         \
    FST_G(0,o0)   FST_G(1,o1)   FST_G(2,o2)   FST_G(3,o3)                    \
    FST_G(4,o4)   FST_G(5,o5)   FST_G(6,o6)   FST_G(7,o7)                    \
    FST_G(8,o8)   FST_G(9,o9)   FST_G(10,o10) FST_G(11,o11)                  \
    FST_G(12,o12) FST_G(13,o13) FST_G(14,o14) FST_G(15,o15) }

#define F_CHUNK(c_, CUR, NXT) {                                \
    const int c = (c_);                                        \
    VMCNT_TOP                /* CUR loads now valid */         \
    F_ISSUE(NXT)             /* next-chunk loads in flight */  \
    if (c >= ca && c <= cb) {                                  \
        const int kb = 16 * c - w16;                           \
        float r0 = NEG, r1 = NEG, r2 = NEG, r3 = NEG,          \
              r4 = NEG, r5 = NEG, r6 = NEG, r7 = NEG,          \
              r8 = NEG, r9 = NEG, r10 = NEG, r11 = NEG,        \
              r12 = NEG, r13 = NEG, r14 = NEG, r15 = NEG;      \
        if (w > 0) {                                           \
            r0  = ring[w - 1][(kb - 1) & 63];                  \
            r1  = ring[w - 1][(kb + 0) & 63];                  \
            r2  = ring[w - 1][(kb + 1) & 63];                  \
            r3  = ring[w - 1][(kb + 2) & 63];                  \
            r4  = ring[w - 1][(kb + 3) & 63];                  \
            r5  = ring[w - 1][(kb + 4) & 63];                  \
            r6  = ring[w - 1][(kb + 5) & 63];                  \
            r7  = ring[w - 1][(kb + 6) & 63];                  \
            r8  = ring[w - 1][(kb + 7) & 63];                  \
            r9  = ring[w - 1][(kb + 8) & 63];                  \
            r10 = ring[w - 1][(kb + 9) & 63];                  \
            r11 = ring[w - 1][(kb + 10) & 63];                 \
            r12 = ring[w - 1][(kb + 11) & 63];                 \
            r13 = ring[w - 1][(kb + 12) & 63];                 \
            r14 = ring[w - 1][(kb + 13) & 63];                 \
            r15 = ring[w - 1][(kb + 14) & 63];                 \
        }                                                      \
        DECL16(o)                                              \
        const int kr = kb - 64 * w;                            \
        if (kr >= 64 && kr <= 496) {                           \
            F_STEPS(I, CUR)                                    \
            F_STORES_I                                         \
        } else {                                               \
            F_STEPS(G, CUR)                                    \
            F_STORES_G                                         \
        }                                                      \
    }                                                          \
    CHUNK_BARRIER                                              \
}

__global__ __launch_bounds__(512, 1)
void nw_forward_kernel(const float2* __restrict__ TAD, float2* __restrict__ pD)
{
    __shared__ float ring[8][64];
    const int b = blockIdx.x;
    const int tid = threadIdx.x;
    const int w = __builtin_amdgcn_readfirstlane(tid >> 6);
    const int lane = tid & 63;
    const int w16 = 16 * w;
    const float2* tab = TAD + (size_t)b * NM;
    float2* pb = pD + (size_t)b * NM;

    for (int x = tid; x < 8 * 64; x += 512) ((float*)ring)[x] = NEG;
    __syncthreads();

    const int ca = 5 * w, cb = 5 * w + 35;

    // streaming address state (byte offsets; SGPR-base loads/stores)
    int kdl = -w16;
    int off8l = tid * 8;                             // extended fi(kd<=0) = tid
    int kds = 64 * w;
    int off8s = (((kds * (kds + 1)) >> 1) + tid) * 8; // fi(64w), 64w<=448<512

    DECL16(fa) DECL16(fb)
    F_ISSUE(fa)

    float vprev = NEG, sh1_d = NEG;

#pragma unroll 1
    for (int c2 = 0; c2 < NCHUNK; c2 += 2) {
        F_CHUNK(c2 + 0, fa, fb)
        F_CHUNK(c2 + 1, fb, fa)
    }
}

// ---------------------------------------------------------------------------
// Backward adjoint, q-product form, mirrored skew (wave 7 leads), K0 = 1134.
// Same rolled-loop + streaming-addressing + batched-store structure.
// Load/store streams descend; delta = (kd<=511 ? -max(kd,0) : min(kd-1023,0)).
// ---------------------------------------------------------------------------
#define BLOAD1(dst) {                                          \
    asm volatile("global_load_dwordx2 %0, %1, %2"              \
                 : "=v"(dst) : "v"(off8l), "s"(pbp));          \
    const int d_ = (kdl <= 511) ? (-max(kdl, 0))               \
                                : min(kdl - 1023, 0);          \
    off8l += d_ * 8; kdl--;                                    \
}
#define B_ISSUE(P) {                                           \
    BLOAD1(P##0)  BLOAD1(P##1)  BLOAD1(P##2)  BLOAD1(P##3)     \
    BLOAD1(P##4)  BLOAD1(P##5)  BLOAD1(P##6)  BLOAD1(P##7)     \
    BLOAD1(P##8)  BLOAD1(P##9)  BLOAD1(P##10) BLOAD1(P##11)    \
    BLOAD1(P##12) BLOAD1(P##13) BLOAD1(P##14) BLOAD1(P##15)    \
}

#define B_CORE(kd_, PP, suv, sdv, EV, TERMFIX) {               \
    float e = suv + sdv + ql1;                                 \
    TERMFIX                                                    \
    const float pu = (PP).x, pl = (PP).y;                      \
    const float pd = 1.0f - pu - pl;                           \
    const float qu = pu * e, qd = pd * e, ql = pl * e;         \
    EV = e;                                                    \
    qd2 = qd1; qd1 = qd; qu1 = qu; ql1 = ql;                   \
    if (lane == 0) {                                           \
        ring_u[w][(kd_) & 63] = qu;                            \
        ring_d[w][(kd_) & 63] = qd;                            \
    }                                                          \
}

#define B_STEP_I(s, PP, EV, RU, RD) {                          \
    const int kd = kb - (s);                                   \
    float su = dpp_shl1(qu1);                                  \
    float sd = dpp_shl1(qd2);                                  \
    if (lane == 63) { su = RU; sd = RD; }                      \
    B_CORE(kd, PP, su, sd, EV, )                               \
}

#define B_STEP_G(s, PP, EV, RU, RD) {                          \
    const int kd = kb - (s);                                   \
    const int jj = kd - tid;                                   \
    float su = dpp_shl1(qu1);                                  \
    float sd = dpp_shl1(qd2);                                  \
    if (lane == 63) { su = RU; sd = RD; }                      \
    if (jj >= 0 && jj < M) {                                   \
        B_CORE(kd, PP, su, sd, EV,                             \
               if (tid == N - 1 && jj == M - 1) e = 1.0f;)     \
    }                                                          \
}

#define B_STEPS(SFX, CUR)                                                          \
    B_STEP_##SFX(0,  CUR##0,  ev0,  ru0,  rd0)  B_STEP_##SFX(1,  CUR##1,  ev1,  ru1,  rd1)  \
    B_STEP_##SFX(2,  CUR##2,  ev2,  ru2,  rd2)  B_STEP_##SFX(3,  CUR##3,  ev3,  ru3,  rd3)  \
    B_STEP_##SFX(4,  CUR##4,  ev4,  ru4,  rd4)  B_STEP_##SFX(5,  CUR##5,  ev5,  ru5,  rd5)  \
    B_STEP_##SFX(6,  CUR##6,  ev6,  ru6,  rd6)  B_STEP_##SFX(7,  CUR##7,  ev7,  ru7,  rd7)  \
    B_STEP_##SFX(8,  CUR##8,  ev8,  ru8,  rd8)  B_STEP_##SFX(9,  CUR##9,  ev9,  ru9,  rd9)  \
    B_STEP_##SFX(10, CUR##10, ev10, ru10, rd10) B_STEP_##SFX(11, CUR##11, ev11, ru11, rd11) \
    B_STEP_##SFX(12, CUR##12, ev12, ru12, rd12) B_STEP_##SFX(13, CUR##13, ev13, ru13, rd13) \
    B_STEP_##SFX(14, CUR##14, ev14, ru14, rd14) B_STEP_##SFX(15, CUR##15, ev15, ru15, rd15)

#define B_ADV_S { const int d_ = (kds <= 511) ? (-max(kds, 0))               \
                                              : min(kds - 1023, 0);          \
                  off4s += d_ * 4; kds--; }
#define BST_I(EV) {                                                          \
    asm volatile("global_store_dword %0, %1, %2"                             \
                 :: "v"(off4s), "v"(EV), "s"(ebp) : "memory");               \
    B_ADV_S }
#define BST_G(s, EV) {                                                       \
    const int jj = kb - (s) - tid;                                           \
    if (jj >= 0 && jj < M) {                                                 \
        asm volatile("global_store_dword %0, %1, %2"                         \
                     :: "v"(off4s), "v"(EV), "s"(ebp) : "memory"); }         \
    B_ADV_S }
#define B_STORES_I {                                                         \
    BST_I(ev0)  BST_I(ev1)  BST_I(ev2)  BST_I(ev3)                           \
    BST_I(ev4)  BST_I(ev5)  BST_I(ev6)  BST_I(ev7)                           \
    BST_I(ev8)  BST_I(ev9)  BST_I(ev10) BST_I(ev11)                          \
    BST_I(ev12) BST_I(ev13) BST_I(ev14) BST_I(ev15) }
#define B_STORES_G {                                                         \
    BST_G(0,ev0)   BST_G(1,ev1)   BST_G(2,ev2)   BST_G(3,ev3)                \
    BST_G(4,ev4)   BST_G(5,ev5)   BST_G(6,ev6)   BST_G(7,ev7)                \
    BST_G(8,ev8)   BST_G(9,ev9)   BST_G(10,ev10) BST_G(11,ev11)              \
    BST_G(12,ev12) BST_G(13,ev13) BST_G(14,ev14) BST_G(15,ev15) }

#define B_CHUNK(c_, CUR, NXT) {                                \
    const int c = (c_);                                        \
    VMCNT_TOP                                                  \
    B_ISSUE(NXT)                                               \
    if (c >= ca && c <= cb) {                                  \
        const int kb = 1134 - 16 * c - w16;                    \
        float ru0 = 0.f, ru1 = 0.f, ru2 = 0.f, ru3 = 0.f,      \
              ru4 = 0.f, ru5 = 0.f, ru6 = 0.f, ru7 = 0.f,      \
              ru8 = 0.f, ru9 = 0.f, ru10 = 0.f, ru11 = 0.f,    \
              ru12 = 0.f, ru13 = 0.f, ru14 = 0.f, ru15 = 0.f;  \
        float rd0 = 0.f, rd1 = 0.f, rd2 = 0.f, rd3 = 0.f,      \
              rd4 = 0.f, rd5 = 0.f, rd6 = 0.f, rd7 = 0.f,      \
              rd8 = 0.f, rd9 = 0.f, rd10 = 0.f, rd11 = 0.f,    \
              rd12 = 0.f, rd13 = 0.f, rd14 = 0.f, rd15 = 0.f;  \
        if (w < 7) {                                           \
            ru0  = ring_u[w + 1][(kb + 1)  & 63]; rd0  = ring_d[w + 1][(kb + 2)  & 63]; \
            ru1  = ring_u[w + 1][(kb + 0)  & 63]; rd1  = ring_d[w + 1][(kb + 1)  & 63]; \
            ru2  = ring_u[w + 1][(kb - 1)  & 63]; rd2  = ring_d[w + 1][(kb + 0)  & 63]; \
            ru3  = ring_u[w + 1][(kb - 2)  & 63]; rd3  = ring_d[w + 1][(kb - 1)  & 63]; \
            ru4  = ring_u[w + 1][(kb - 3)  & 63]; rd4  = ring_d[w + 1][(kb - 2)  & 63]; \
            ru5  = ring_u[w + 1][(kb - 4)  & 63]; rd5  = ring_d[w + 1][(kb - 3)  & 63]; \
            ru6  = ring_u[w + 1][(kb - 5)  & 63]; rd6  = ring_d[w + 1][(kb - 4)  & 63]; \
            ru7  = ring_u[w + 1][(kb - 6)  & 63]; rd7  = ring_d[w + 1][(kb - 5)  & 63]; \
            ru8  = ring_u[w + 1][(kb - 7)  & 63]; rd8  = ring_d[w + 1][(kb - 6)  & 63]; \
            ru9  = ring_u[w + 1][(kb - 8)  & 63]; rd9  = ring_d[w + 1][(kb - 7)  & 63]; \
            ru10 = ring_u[w + 1][(kb - 9)  & 63]; rd10 = ring_d[w + 1][(kb - 8)  & 63]; \
            ru11 = ring_u[w + 1][(kb - 10) & 63]; rd11 = ring_d[w + 1][(kb - 9)  & 63]; \
            ru12 = ring_u[w + 1][(kb - 11) & 63]; rd12 = ring_d[w + 1][(kb - 10) & 63]; \
            ru13 = ring_u[w + 1][(kb - 12) & 63]; rd13 = ring_d[w + 1][(kb - 11) & 63]; \
            ru14 = ring_u[w + 1][(kb - 13) & 63]; rd14 = ring_d[w + 1][(kb - 12) & 63]; \
            ru15 = ring_u[w + 1][(kb - 14) & 63]; rd15 = ring_d[w + 1][(kb - 13) & 63]; \
        }                                                      \
        DECL16F(ev)                                            \
        const int krb = kb - 64 * w;                           \
        if (krb >= 78 && krb <= 511) {                         \
            B_STEPS(I, CUR)                                    \
            B_STORES_I                                         \
        } else {                                               \
            B_STEPS(G, CUR)                                    \
            B_STORES_G                                         \
        }                                                      \
    }                                                          \
    CHUNK_BARRIER                                              \
}

__global__ __launch_bounds__(512, 1)
void nw_backward_kernel(const float2* __restrict__ pD, float* __restrict__ ED)
{
    __shared__ float ring_u[8][64];
    __shared__ float ring_d[8][64];
    const int b = blockIdx.x;
    const int tid = threadIdx.x;
    const int w = __builtin_amdgcn_readfirstlane(tid >> 6);
    const int lane = tid & 63;
    const int w16 = 16 * w;
    const float2* pbp = pD + (size_t)b * NM;
    float* ebp = ED + (size_t)b * NM;

    for (int x = tid; x < 8 * 64; x += 512) {
        ((float*)ring_u)[x] = 0.0f;
        ((float*)ring_d)[x] = 0.0f;
    }
    __syncthreads();

    const int ca = 35 - 5 * w, cb = 70 - 5 * w;

    // streaming address state (descending)
    int kdl = 1134 - w16;
    int off8l = ((int)NM - 512 + tid) * 8;           // fi(1022)
    int kds = 574 + 64 * w;                          // first active store kd
    const int am_ = 1023 - kds, bm_ = 1024 - kds;
    int off4s = ((int)NM - ((am_ * bm_) >> 1) + tid - (kds - 511)) * 4;

    DECL16(ba) DECL16(bb)
    B_ISSUE(ba)

    float qu1 = 0.0f, qd1 = 0.0f, qd2 = 0.0f, ql1 = 0.0f;

#pragma unroll 1
    for (int c2 = 0; c2 < NCHUNK; c2 += 2) {
        B_CHUNK(c2 + 0, ba, bb)
        B_CHUNK(c2 + 1, bb, ba)
    }
}

// ---------------------------------------------------------------------------
extern "C" void kernel_launch(void* const* d_in, const int* in_sizes, int n_in,
                              void* d_out, int out_size, void* d_ws, size_t ws_size,
                              hipStream_t stream) {
    const float* zx = (const float*)d_in[0];
    const float* zy = (const float*)d_in[1];
    const float* gx = (const float*)d_in[2];
    const float* gy = (const float*)d_in[3];

    float* aln   = (float*)d_out;               // output 0: [B,N,M]
    float* theta = aln + B * NM;                // output 1
    float* Amat  = theta + B * NM;              // output 2

    float2* TAD = (float2*)d_ws;                // {theta,A}*log2e diag-interleaved
    float2* pD  = TAD + B * NM;                 // {p_up,p_lf} diag-interleaved
    float*  ED  = (float*)d_ws;                 // overlays TAD (dead after forward)

    gemm_act_kernel<<<dim3(8, 8, B * 2), dim3(16, 16), 0, stream>>>(zx, zy, gx, gy, theta, Amat);
    reorder_in_kernel<<<dim3(8, 8, B), 256, 0, stream>>>(theta, Amat, TAD);
    nw_forward_kernel<<<B, 512, 0, stream>>>(TAD, pD);
    nw_backward_kernel<<<B, 512, 0, stream>>>(pD, ED);
    reorder_out_kernel<<<dim3(8, 8, B), 256, 0, stream>>>(ED, aln);
}